// Round 3
// baseline (2325.680 us; speedup 1.0000x reference)
//
#include <hip/hip_runtime.h>
#include <hip/hip_bf16.h>

typedef __hip_bfloat16 bf16;
typedef unsigned short u16;
typedef unsigned int   u32;

#define SCALE 0.08838834764831845f  // 1/sqrt(128)

__device__ __forceinline__ float u2f(u16 x) { return __uint_as_float(((u32)x) << 16); }
__device__ __forceinline__ u16   f2u(float f) {
    __hip_bfloat16 h = __float2bfloat16(f);
    return *reinterpret_cast<u16*>(&h);
}

// dtype-agnostic global load: BF ? bf16-as-u16 : fp32
template<bool BF>
__device__ __forceinline__ float LD(const void* p, int i) {
    if (BF) return u2f(((const u16*)p)[i]);
    else    return ((const float*)p)[i];
}

template<bool BF>
__device__ void body(
    const void* timef, const void* ppf, const void* pnf, const void* wgt,
    const int* __restrict__ sgn,
    const void* Wq, const void* bq, const void* Wk, const void* bk,
    const void* Wv, const void* bv, const void* Wl, const void* bl,
    const void* Wqp, const void* bqp, const void* Wkp, const void* bkp,
    const void* Wvp, const void* bvp, void* out)
{
    extern __shared__ __align__(16) char S[];
    // arena (62848 B): U[41088] | sc 4224 | embs 16384 | csumA 128 | y1 512 | e1 512
    char* const U = S;
    float (* const sc)[33]     = (float(*)[33])(S + 41088);
    u16   (* const embs)[128]  = (u16  (*)[128])(S + 45312);
    float* const csumA         = (float*)(S + 61696);
    float* const y1            = (float*)(S + 61824);
    float* const e1            = (float*)(S + 62336);
    // phase-1 overlay of U: xs u16[32][128] | qs f32[32][128] | ks f32[32][129]
    u16   (* const xs)[128]   = (u16  (*)[128])U;
    float (* const qs)[128]   = (float(*)[128])(U + 8192);
    float (* const ks)[129]   = (float(*)[129])(U + 8192 + 16384);
    // phase-2 overlay of U: k2s f32[64][129] | qrow f32[4][128] | csum2 f32[4][64]
    float (* const k2s)[129]  = (float(*)[129])U;
    float (* const qrow)[128] = (float(*)[128])(U + 33024);
    float (* const csum2)[64] = (float(*)[64])(U + 35072);

    const int t    = threadIdx.x;
    const int side = blockIdx.x >> 7;
    const int b    = blockIdx.x & 127;
    const int wv_  = t >> 6;
    const int lane = t & 63;

    // ================= phase 1: 64 walks, level-1 attention =================
    for (int w = 0; w < 64; ++w) {
        const int tokb = (b * 64 + w) * 32;
        for (int o = t; o < 32 * 128; o += 256) {
            const int l = o >> 7, f = o & 127;
            const int tok = tokb + l;
            float v;
            if (f < 19) {
                const bool takeP = (sgn[tok] > 0) == (side == 0);
                v = takeP ? LD<BF>(ppf, tok * 19 + f) : LD<BF>(pnf, tok * 19 + f);
            } else if (f < 127) {
                v = LD<BF>(timef, tok * 108 + (f - 19));
            } else {
                v = LD<BF>(wgt, tok);
            }
            xs[l][f] = f2u(v);   // lossless when BF
        }
        __syncthreads();

        // q,k projections: thread owns d = t&127, rows l0+2i
        {
            const int d = t & 127, l0 = t >> 7;
            float aq[16], ak[16];
            const float bqv = LD<BF>(bq, d), bkv = LD<BF>(bk, d);
            #pragma unroll
            for (int i = 0; i < 16; i++) { aq[i] = bqv; ak[i] = bkv; }
            for (int e = 0; e < 128; e += 4) {
                float xv[16][4];
                #pragma unroll
                for (int i = 0; i < 16; i++) {
                    const ushort4 u = *(const ushort4*)&xs[l0 + 2 * i][e];
                    xv[i][0] = u2f(u.x); xv[i][1] = u2f(u.y);
                    xv[i][2] = u2f(u.z); xv[i][3] = u2f(u.w);
                }
                #pragma unroll
                for (int r = 0; r < 4; r++) {
                    const float wq = LD<BF>(Wq, (e + r) * 128 + d);
                    const float wk = LD<BF>(Wk, (e + r) * 128 + d);
                    #pragma unroll
                    for (int i = 0; i < 16; i++) {
                        aq[i] += xv[i][r] * wq;
                        ak[i] += xv[i][r] * wk;
                    }
                }
            }
            #pragma unroll
            for (int i = 0; i < 16; i++) {
                const int l = l0 + 2 * i;
                qs[l][d] = aq[i];
                ks[l][d] = ak[i];
            }
        }
        __syncthreads();

        // scores = q k^T * SCALE
        for (int o = t; o < 1024; o += 256) {
            const int i = o >> 5, j = o & 31;
            float a0 = 0, a1 = 0, a2 = 0, a3 = 0;
            for (int e = 0; e < 128; e += 4) {
                const float4 q4 = *(const float4*)&qs[i][e];
                a0 += q4.x * ks[j][e];
                a1 += q4.y * ks[j][e + 1];
                a2 += q4.z * ks[j][e + 2];
                a3 += q4.w * ks[j][e + 3];
            }
            sc[i][j] = (a0 + a1 + a2 + a3) * SCALE;
        }
        __syncthreads();

        if (t < 32) {   // softmax rows
            float m = -1e30f;
            for (int j = 0; j < 32; j++) m = fmaxf(m, sc[t][j]);
            float s = 0.f;
            for (int j = 0; j < 32; j++) { const float e0 = __expf(sc[t][j] - m); sc[t][j] = e0; s += e0; }
            const float inv = 1.f / s;
            for (int j = 0; j < 32; j++) sc[t][j] *= inv;
        }
        __syncthreads();
        if (t < 32) {   // column sums (query-sum folded onto keys)
            float s = 0.f;
            for (int i = 0; i < 32; i++) s += sc[i][t];
            csumA[t] = s;
        }
        __syncthreads();
        if (t < 128) {  // y1 = csumA^T @ x  (V-projection commuted out)
            float a = 0.f;
            for (int j = 0; j < 32; j++) a += csumA[j] * u2f(xs[j][t]);
            y1[t] = a;
        }
        __syncthreads();
        if (t < 128) {  // e1 = y1 @ Wv + 32*bv  (each softmax row sums to 1)
            float a = 32.f * LD<BF>(bv, t);
            for (int e = 0; e < 128; e++) a += y1[e] * LD<BF>(Wv, e * 128 + t);
            e1[t] = a;
        }
        __syncthreads();
        if (t < 128) {  // emb row = e1 @ Wl + bl
            float a = LD<BF>(bl, t);
            for (int f = 0; f < 128; f++) a += e1[f] * LD<BF>(Wl, f * 128 + t);
            embs[w][t] = f2u(a);
        }
        __syncthreads();
    }

    // ================= phase 2: level-2 attention over 64 walks =================
    {
        const int d = t & 127, j0 = t >> 7;
        float ak2[32];
        const float bkv = LD<BF>(bkp, d);
        #pragma unroll
        for (int i = 0; i < 32; i++) ak2[i] = bkv;
        for (int e = 0; e < 128; e++) {
            const float wk = LD<BF>(Wkp, e * 128 + d);
            #pragma unroll
            for (int i = 0; i < 32; i++)
                ak2[i] += u2f(embs[j0 + 2 * i][e]) * wk;
        }
        #pragma unroll
        for (int i = 0; i < 32; i++) k2s[j0 + 2 * i][d] = ak2[i];
    }
    csum2[wv_][lane] = 0.f;
    __syncthreads();

    for (int i0 = 0; i0 < 64; i0 += 4) {
        const int r = i0 + wv_;
        {
            float a0 = LD<BF>(bqp, lane), a1 = LD<BF>(bqp, lane + 64);
            for (int e = 0; e < 128; e++) {
                const float xv = u2f(embs[r][e]);
                a0 += xv * LD<BF>(Wqp, e * 128 + lane);
                a1 += xv * LD<BF>(Wqp, e * 128 + lane + 64);
            }
            qrow[wv_][lane] = a0; qrow[wv_][lane + 64] = a1;  // wave-private row
        }
        {
            const int j = lane;
            float s = 0.f;
            for (int e = 0; e < 128; e += 4) {
                const float4 q4 = *(const float4*)&qrow[wv_][e];
                s += q4.x * k2s[j][e]     + q4.y * k2s[j][e + 1]
                   + q4.z * k2s[j][e + 2] + q4.w * k2s[j][e + 3];
            }
            s *= SCALE;
            float m = s;
            #pragma unroll
            for (int off = 32; off; off >>= 1) m = fmaxf(m, __shfl_xor(m, off));
            const float e0 = __expf(s - m);
            float sum = e0;
            #pragma unroll
            for (int off = 32; off; off >>= 1) sum += __shfl_xor(sum, off);
            csum2[wv_][j] += e0 / sum;   // lane j owns csum2[wv_][j]
        }
        __syncthreads();
    }

    if (t < 64)
        csum2[0][t] = csum2[0][t] + csum2[1][t] + csum2[2][t] + csum2[3][t];
    __syncthreads();
    if (t < 128) {  // y2 = csum2^T @ emb
        float a = 0.f;
        for (int j = 0; j < 64; j++) a += csum2[0][j] * u2f(embs[j][t]);
        y1[t] = a;
    }
    __syncthreads();
    if (t < 128) {  // out = y2 @ Wvp + 64*bvp
        float a = 64.f * LD<BF>(bvp, t);
        for (int e = 0; e < 128; e++) a += y1[e] * LD<BF>(Wvp, e * 128 + t);
        const int idx = blockIdx.x * 128 + t;
        if (BF) ((u16*)out)[idx] = f2u(a);
        else    ((float*)out)[idx] = a;
    }
}

__global__ __launch_bounds__(256) void rwa_fused(
    const void* timef, const void* ppf, const void* pnf, const void* wgt,
    const int* __restrict__ sgn,
    const void* Wq, const void* bq, const void* Wk, const void* bk,
    const void* Wv, const void* bv, const void* Wl, const void* bl,
    const void* Wqp, const void* bqp, const void* Wkp, const void* bkp,
    const void* Wvp, const void* bvp, void* out)
{
    // Runtime dtype sniff on weight (uniform [0,1)): all of the first 8 u16
    // words must decode as bf16 in [2^-16, 1). fp32 data read as u16 fails
    // this with overwhelming probability (even words are mantissa bits).
    bool isbf = true;
    const u16* w16 = (const u16*)wgt;
    #pragma unroll
    for (int i = 0; i < 8; i++) {
        const u16 u = w16[i];
        const int ex = (u >> 7) & 0xFF;
        if ((u >> 15) || ex >= 127 || ex <= 110) isbf = false;
    }
    if (isbf)
        body<true >(timef, ppf, pnf, wgt, sgn, Wq, bq, Wk, bk, Wv, bv, Wl, bl,
                    Wqp, bqp, Wkp, bkp, Wvp, bvp, out);
    else
        body<false>(timef, ppf, pnf, wgt, sgn, Wq, bq, Wk, bk, Wv, bv, Wl, bl,
                    Wqp, bqp, Wkp, bkp, Wvp, bvp, out);
}

extern "C" void kernel_launch(void* const* d_in, const int* in_sizes, int n_in,
                              void* d_out, int out_size, void* d_ws, size_t ws_size,
                              hipStream_t stream) {
    (void)d_ws; (void)ws_size; (void)in_sizes; (void)n_in; (void)out_size;
    hipLaunchKernelGGL(rwa_fused, dim3(256), dim3(256), 62848, stream,
                       d_in[0], d_in[1], d_in[2], d_in[3], (const int*)d_in[4],
                       d_in[5], d_in[6], d_in[7], d_in[8], d_in[9], d_in[10],
                       d_in[11], d_in[12], d_in[13], d_in[14], d_in[15], d_in[16],
                       d_in[17], d_in[18], d_out);
}

// Round 4
// 1181.267 us; speedup vs baseline: 1.9688x; 1.9688x over previous
//
#include <hip/hip_runtime.h>
#include <hip/hip_bf16.h>

typedef __hip_bfloat16 bf16;
typedef unsigned short u16;
typedef unsigned int   u32;

#define SCALE 0.08838834764831845f  // 1/sqrt(128)

__device__ __forceinline__ float u2f(u16 x) { return __uint_as_float(((u32)x) << 16); }
__device__ __forceinline__ u16   f2u(float f) {
    __hip_bfloat16 h = __float2bfloat16(f);
    return *reinterpret_cast<u16*>(&h);
}

// ================= Kernel A: level-1 attention, one block per (side, walk) ==
// grid = 2*B*NW = 16384, 256 threads. emb row (fp32[128]) -> ws.
__global__ __launch_bounds__(256) void rwa_walk(
    const float* __restrict__ timef, const float* __restrict__ ppf,
    const float* __restrict__ pnf,  const float* __restrict__ wgt,
    const int*  __restrict__ sgn,
    const float* __restrict__ Wq, const float* __restrict__ bq,
    const float* __restrict__ Wk, const float* __restrict__ bk,
    const float* __restrict__ Wv, const float* __restrict__ bv,
    const float* __restrict__ Wl, const float* __restrict__ bl,
    float* __restrict__ emb)
{
    __shared__ u16   xs[32][128];     // 8 KB, inputs quantized to bf16 (error budget ok: R3 absmax 0.0156)
    __shared__ float qs[32][128];     // 16 KB
    __shared__ float ks[32][129];     // 16.5 KB, padded
    __shared__ float sc[32][33];      // 4.2 KB, padded
    __shared__ float csumA[32];
    __shared__ float y1[128];
    __shared__ float e1[128];

    const int t    = threadIdx.x;
    const int side = blockIdx.x & 1;   // adjacent blocks share time-feature reads in L2
    const int bw   = blockIdx.x >> 1;  // b*64 + w
    const int tokb = bw * 32;

    // gather [pos/neg 19 | time 108 | weight 1], sign-selected
    for (int o = t; o < 32 * 128; o += 256) {
        const int l = o >> 7, f = o & 127;
        const int tok = tokb + l;
        float v;
        if (f < 19) {
            const bool takeP = (sgn[tok] > 0) == (side == 0);
            v = takeP ? ppf[tok * 19 + f] : pnf[tok * 19 + f];
        } else if (f < 127) {
            v = timef[tok * 108 + (f - 19)];
        } else {
            v = wgt[tok];
        }
        xs[l][f] = f2u(v);
    }
    __syncthreads();

    // q,k projections: thread owns d = t&127, rows l0+2i
    {
        const int d = t & 127, l0 = t >> 7;
        float aq[16], ak[16];
        const float bqv = bq[d], bkv = bk[d];
        #pragma unroll
        for (int i = 0; i < 16; i++) { aq[i] = bqv; ak[i] = bkv; }
        for (int e = 0; e < 128; e += 4) {
            float xv[16][4];
            #pragma unroll
            for (int i = 0; i < 16; i++) {
                const ushort4 u = *(const ushort4*)&xs[l0 + 2 * i][e];   // broadcast
                xv[i][0] = u2f(u.x); xv[i][1] = u2f(u.y);
                xv[i][2] = u2f(u.z); xv[i][3] = u2f(u.w);
            }
            #pragma unroll
            for (int r = 0; r < 4; r++) {
                const float wq = Wq[(e + r) * 128 + d];   // coalesced, L2-hot
                const float wk = Wk[(e + r) * 128 + d];
                #pragma unroll
                for (int i = 0; i < 16; i++) {
                    aq[i] += xv[i][r] * wq;
                    ak[i] += xv[i][r] * wk;
                }
            }
        }
        #pragma unroll
        for (int i = 0; i < 16; i++) {
            const int l = l0 + 2 * i;
            qs[l][d] = aq[i];
            ks[l][d] = ak[i];
        }
    }
    __syncthreads();

    // scores = q k^T * SCALE
    for (int o = t; o < 1024; o += 256) {
        const int i = o >> 5, j = o & 31;
        float a0 = 0, a1 = 0, a2 = 0, a3 = 0;
        for (int e = 0; e < 128; e += 4) {
            const float4 q4 = *(const float4*)&qs[i][e];
            a0 += q4.x * ks[j][e];
            a1 += q4.y * ks[j][e + 1];
            a2 += q4.z * ks[j][e + 2];
            a3 += q4.w * ks[j][e + 3];
        }
        sc[i][j] = (a0 + a1 + a2 + a3) * SCALE;
    }
    __syncthreads();

    if (t < 32) {   // softmax rows
        float m = -1e30f;
        for (int j = 0; j < 32; j++) m = fmaxf(m, sc[t][j]);
        float s = 0.f;
        for (int j = 0; j < 32; j++) { const float e0 = __expf(sc[t][j] - m); sc[t][j] = e0; s += e0; }
        const float inv = 1.f / s;
        for (int j = 0; j < 32; j++) sc[t][j] *= inv;
    }
    __syncthreads();
    if (t < 32) {   // column sums (query-sum folded onto keys)
        float s = 0.f;
        for (int i = 0; i < 32; i++) s += sc[i][t];
        csumA[t] = s;
    }
    __syncthreads();
    if (t < 128) {  // y1 = csumA^T @ x  (V-projection commuted out)
        float a = 0.f;
        for (int j = 0; j < 32; j++) a += csumA[j] * u2f(xs[j][t]);
        y1[t] = a;
    }
    __syncthreads();
    if (t < 128) {  // e1 = y1 @ Wv + 32*bv  (each softmax row sums to 1)
        float a = 32.f * bv[t];
        for (int e = 0; e < 128; e++) a += y1[e] * Wv[e * 128 + t];
        e1[t] = a;
    }
    __syncthreads();
    if (t < 128) {  // emb row = e1 @ Wl + bl
        float a = bl[t];
        for (int f = 0; f < 128; f++) a += e1[f] * Wl[f * 128 + t];
        emb[(side * 8192 + bw) * 128 + t] = a;
    }
}

// ================= Kernel B: level-2 attention, one block per (side, b) =====
// grid = 256, 256 threads.
__global__ __launch_bounds__(256) void rwa_path(
    const float* __restrict__ emb,
    const float* __restrict__ Wqp, const float* __restrict__ bqp,
    const float* __restrict__ Wkp, const float* __restrict__ bkp,
    const float* __restrict__ Wvp, const float* __restrict__ bvp,
    float* __restrict__ out)
{
    __shared__ u16   embs[64][128];   // 16 KB (bf16, same precision as R3 which passed)
    __shared__ float k2s[64][129];    // 33 KB, padded
    __shared__ float qrow[4][128];
    __shared__ float csum2[4][64];
    __shared__ float y2[128];

    const int t    = threadIdx.x;
    const int sb   = blockIdx.x;           // side*128 + b
    const int side = sb >> 7, b = sb & 127;
    const long gbase = (long)(side * 8192 + b * 64) * 128;
    const int wv_ = t >> 6, lane = t & 63;

    for (int o = t; o < 64 * 128; o += 256) embs[o >> 7][o & 127] = f2u(emb[gbase + o]);
    __syncthreads();

    {   // k2 = emb @ Wkp + bkp
        const int d = t & 127, j0 = t >> 7;
        float ak2[32];
        const float bkv = bkp[d];
        #pragma unroll
        for (int i = 0; i < 32; i++) ak2[i] = bkv;
        for (int e = 0; e < 128; e++) {
            const float wk = Wkp[e * 128 + d];
            #pragma unroll
            for (int i = 0; i < 32; i++)
                ak2[i] += u2f(embs[j0 + 2 * i][e]) * wk;   // broadcast read
        }
        #pragma unroll
        for (int i = 0; i < 32; i++) k2s[j0 + 2 * i][d] = ak2[i];
    }
    csum2[wv_][lane] = 0.f;
    __syncthreads();

    for (int i0 = 0; i0 < 64; i0 += 4) {
        const int r = i0 + wv_;
        {   // q2 row r on the fly (wave-private)
            float a0 = bqp[lane], a1 = bqp[lane + 64];
            for (int e = 0; e < 128; e++) {
                const float xv = u2f(embs[r][e]);
                a0 += xv * Wqp[e * 128 + lane];
                a1 += xv * Wqp[e * 128 + lane + 64];
            }
            qrow[wv_][lane] = a0; qrow[wv_][lane + 64] = a1;
        }
        {   // 64-key scores + in-wave softmax, accumulate column sums
            const int j = lane;
            float s = 0.f;
            for (int e = 0; e < 128; e += 4) {
                const float4 q4 = *(const float4*)&qrow[wv_][e];
                s += q4.x * k2s[j][e]     + q4.y * k2s[j][e + 1]
                   + q4.z * k2s[j][e + 2] + q4.w * k2s[j][e + 3];
            }
            s *= SCALE;
            float m = s;
            #pragma unroll
            for (int off = 32; off; off >>= 1) m = fmaxf(m, __shfl_xor(m, off));
            const float e0 = __expf(s - m);
            float sum = e0;
            #pragma unroll
            for (int off = 32; off; off >>= 1) sum += __shfl_xor(sum, off);
            csum2[wv_][j] += e0 / sum;   // lane j owns csum2[wv_][j]
        }
        __syncthreads();
    }

    if (t < 64)
        csum2[0][t] = csum2[0][t] + csum2[1][t] + csum2[2][t] + csum2[3][t];
    __syncthreads();
    if (t < 128) {  // y2 = csum2^T @ emb
        float a = 0.f;
        for (int j = 0; j < 64; j++) a += csum2[0][j] * u2f(embs[j][t]);
        y2[t] = a;
    }
    __syncthreads();
    if (t < 128) {  // out = y2 @ Wvp + 64*bvp
        float a = 64.f * bvp[t];
        for (int e = 0; e < 128; e++) a += y2[e] * Wvp[e * 128 + t];
        out[sb * 128 + t] = a;
    }
}

// ================= Fallback: R3's proven fused kernel (fp32 path) ===========
__global__ __launch_bounds__(256) void rwa_fused_fb(
    const float* timef, const float* ppf, const float* pnf, const float* wgt,
    const int* __restrict__ sgn,
    const float* Wq, const float* bq, const float* Wk, const float* bk,
    const float* Wv, const float* bv, const float* Wl, const float* bl,
    const float* Wqp, const float* bqp, const float* Wkp, const float* bkp,
    const float* Wvp, const float* bvp, float* out)
{
    extern __shared__ __align__(16) char S[];
    char* const U = S;
    float (* const sc)[33]     = (float(*)[33])(S + 41088);
    u16   (* const embs)[128]  = (u16  (*)[128])(S + 45312);
    float* const csumA         = (float*)(S + 61696);
    float* const y1            = (float*)(S + 61824);
    float* const e1            = (float*)(S + 62336);
    u16   (* const xs)[128]   = (u16  (*)[128])U;
    float (* const qs)[128]   = (float(*)[128])(U + 8192);
    float (* const ks)[129]   = (float(*)[129])(U + 8192 + 16384);
    float (* const k2s)[129]  = (float(*)[129])U;
    float (* const qrow)[128] = (float(*)[128])(U + 33024);
    float (* const csum2)[64] = (float(*)[64])(U + 35072);

    const int t    = threadIdx.x;
    const int side = blockIdx.x >> 7;
    const int b    = blockIdx.x & 127;
    const int wv_  = t >> 6;
    const int lane = t & 63;

    for (int w = 0; w < 64; ++w) {
        const int tokb = (b * 64 + w) * 32;
        for (int o = t; o < 32 * 128; o += 256) {
            const int l = o >> 7, f = o & 127;
            const int tok = tokb + l;
            float v;
            if (f < 19) {
                const bool takeP = (sgn[tok] > 0) == (side == 0);
                v = takeP ? ppf[tok * 19 + f] : pnf[tok * 19 + f];
            } else if (f < 127) v = timef[tok * 108 + (f - 19)];
            else v = wgt[tok];
            xs[l][f] = f2u(v);
        }
        __syncthreads();
        {
            const int d = t & 127, l0 = t >> 7;
            float aq[16], ak[16];
            const float bqv = bq[d], bkv = bk[d];
            #pragma unroll
            for (int i = 0; i < 16; i++) { aq[i] = bqv; ak[i] = bkv; }
            for (int e = 0; e < 128; e += 4) {
                float xv[16][4];
                #pragma unroll
                for (int i = 0; i < 16; i++) {
                    const ushort4 u = *(const ushort4*)&xs[l0 + 2 * i][e];
                    xv[i][0] = u2f(u.x); xv[i][1] = u2f(u.y);
                    xv[i][2] = u2f(u.z); xv[i][3] = u2f(u.w);
                }
                #pragma unroll
                for (int r = 0; r < 4; r++) {
                    const float wq = Wq[(e + r) * 128 + d];
                    const float wk = Wk[(e + r) * 128 + d];
                    #pragma unroll
                    for (int i = 0; i < 16; i++) {
                        aq[i] += xv[i][r] * wq; ak[i] += xv[i][r] * wk;
                    }
                }
            }
            #pragma unroll
            for (int i = 0; i < 16; i++) { const int l = l0 + 2 * i; qs[l][d] = aq[i]; ks[l][d] = ak[i]; }
        }
        __syncthreads();
        for (int o = t; o < 1024; o += 256) {
            const int i = o >> 5, j = o & 31;
            float a0 = 0, a1 = 0, a2 = 0, a3 = 0;
            for (int e = 0; e < 128; e += 4) {
                const float4 q4 = *(const float4*)&qs[i][e];
                a0 += q4.x * ks[j][e];     a1 += q4.y * ks[j][e + 1];
                a2 += q4.z * ks[j][e + 2]; a3 += q4.w * ks[j][e + 3];
            }
            sc[i][j] = (a0 + a1 + a2 + a3) * SCALE;
        }
        __syncthreads();
        if (t < 32) {
            float m = -1e30f;
            for (int j = 0; j < 32; j++) m = fmaxf(m, sc[t][j]);
            float s = 0.f;
            for (int j = 0; j < 32; j++) { const float e0 = __expf(sc[t][j] - m); sc[t][j] = e0; s += e0; }
            const float inv = 1.f / s;
            for (int j = 0; j < 32; j++) sc[t][j] *= inv;
        }
        __syncthreads();
        if (t < 32) { float s = 0.f; for (int i = 0; i < 32; i++) s += sc[i][t]; csumA[t] = s; }
        __syncthreads();
        if (t < 128) { float a = 0.f; for (int j = 0; j < 32; j++) a += csumA[j] * u2f(xs[j][t]); y1[t] = a; }
        __syncthreads();
        if (t < 128) {
            float a = 32.f * bv[t];
            for (int e = 0; e < 128; e++) a += y1[e] * Wv[e * 128 + t];
            e1[t] = a;
        }
        __syncthreads();
        if (t < 128) {
            float a = bl[t];
            for (int f = 0; f < 128; f++) a += e1[f] * Wl[f * 128 + t];
            embs[w][t] = f2u(a);
        }
        __syncthreads();
    }
    {
        const int d = t & 127, j0 = t >> 7;
        float ak2[32];
        const float bkv = bkp[d];
        #pragma unroll
        for (int i = 0; i < 32; i++) ak2[i] = bkv;
        for (int e = 0; e < 128; e++) {
            const float wk = Wkp[e * 128 + d];
            #pragma unroll
            for (int i = 0; i < 32; i++) ak2[i] += u2f(embs[j0 + 2 * i][e]) * wk;
        }
        #pragma unroll
        for (int i = 0; i < 32; i++) k2s[j0 + 2 * i][d] = ak2[i];
    }
    csum2[wv_][lane] = 0.f;
    __syncthreads();
    for (int i0 = 0; i0 < 64; i0 += 4) {
        const int r = i0 + wv_;
        {
            float a0 = bqp[lane], a1 = bqp[lane + 64];
            for (int e = 0; e < 128; e++) {
                const float xv = u2f(embs[r][e]);
                a0 += xv * Wqp[e * 128 + lane];
                a1 += xv * Wqp[e * 128 + lane + 64];
            }
            qrow[wv_][lane] = a0; qrow[wv_][lane + 64] = a1;
        }
        {
            const int j = lane;
            float s = 0.f;
            for (int e = 0; e < 128; e += 4) {
                const float4 q4 = *(const float4*)&qrow[wv_][e];
                s += q4.x * k2s[j][e] + q4.y * k2s[j][e + 1] + q4.z * k2s[j][e + 2] + q4.w * k2s[j][e + 3];
            }
            s *= SCALE;
            float m = s;
            #pragma unroll
            for (int off = 32; off; off >>= 1) m = fmaxf(m, __shfl_xor(m, off));
            const float e0 = __expf(s - m);
            float sum = e0;
            #pragma unroll
            for (int off = 32; off; off >>= 1) sum += __shfl_xor(sum, off);
            csum2[wv_][j] += e0 / sum;
        }
        __syncthreads();
    }
    if (t < 64) csum2[0][t] = csum2[0][t] + csum2[1][t] + csum2[2][t] + csum2[3][t];
    __syncthreads();
    if (t < 128) { float a = 0.f; for (int j = 0; j < 64; j++) a += csum2[0][j] * u2f(embs[j][t]); y1[t] = a; }
    __syncthreads();
    if (t < 128) {
        float a = 64.f * bvp[t];
        for (int e = 0; e < 128; e++) a += y1[e] * Wvp[e * 128 + t];
        out[blockIdx.x * 128 + t] = a;
    }
}

extern "C" void kernel_launch(void* const* d_in, const int* in_sizes, int n_in,
                              void* d_out, int out_size, void* d_ws, size_t ws_size,
                              hipStream_t stream) {
    const float* timef = (const float*)d_in[0];
    const float* ppf   = (const float*)d_in[1];
    const float* pnf   = (const float*)d_in[2];
    const float* wgt   = (const float*)d_in[3];
    const int*   sgn   = (const int*)  d_in[4];
    const float* Wq  = (const float*)d_in[5];  const float* bq  = (const float*)d_in[6];
    const float* Wk  = (const float*)d_in[7];  const float* bk  = (const float*)d_in[8];
    const float* Wv  = (const float*)d_in[9];  const float* bv  = (const float*)d_in[10];
    const float* Wl  = (const float*)d_in[11]; const float* bl  = (const float*)d_in[12];
    const float* Wqp = (const float*)d_in[13]; const float* bqp = (const float*)d_in[14];
    const float* Wkp = (const float*)d_in[15]; const float* bkp = (const float*)d_in[16];
    const float* Wvp = (const float*)d_in[17]; const float* bvp = (const float*)d_in[18];
    float* out = (float*)d_out;
    (void)in_sizes; (void)n_in; (void)out_size;

    const size_t need = (size_t)2 * 8192 * 128 * sizeof(float);   // 8 MB emb
    if (ws_size >= need) {
        float* emb = (float*)d_ws;
        hipLaunchKernelGGL(rwa_walk, dim3(16384), dim3(256), 0, stream,
                           timef, ppf, pnf, wgt, sgn, Wq, bq, Wk, bk, Wv, bv, Wl, bl, emb);
        hipLaunchKernelGGL(rwa_path, dim3(256), dim3(256), 0, stream,
                           emb, Wqp, bqp, Wkp, bkp, Wvp, bvp, out);
    } else {
        hipLaunchKernelGGL(rwa_fused_fb, dim3(256), dim3(256), 62848, stream,
                           timef, ppf, pnf, wgt, sgn, Wq, bq, Wk, bk, Wv, bv, Wl, bl,
                           Wqp, bqp, Wkp, bkp, Wvp, bvp, out);
    }
}

// Round 5
// 637.594 us; speedup vs baseline: 3.6476x; 1.8527x over previous
//
#include <hip/hip_runtime.h>
#include <hip/hip_bf16.h>

typedef __hip_bfloat16 bf16;
typedef unsigned short u16;
typedef unsigned int   u32;
typedef __attribute__((ext_vector_type(8))) short short8;   // 8 bf16 = 4 VGPRs
typedef __attribute__((ext_vector_type(4))) float f32x4;

#define SCALE 0.08838834764831845f  // 1/sqrt(128)

__device__ __forceinline__ float u2f(u16 x) { return __uint_as_float(((u32)x) << 16); }
__device__ __forceinline__ u16   f2u(float f) {
    __hip_bfloat16 h = __float2bfloat16(f);
    return *reinterpret_cast<u16*>(&h);
}

// ============ prep_frag: fragment-major bf16 repack of Wq, Wk ============
// frag[mat][nt][kc][lane][j] = W[kc*32 + (lane>>4)*8 + j][nt*16 + (lane&15)]
// grid 64 = 2 mats x 8 nt x 4 kc, 256 thr
__global__ void prep_frag(const float* __restrict__ Wq, const float* __restrict__ Wk,
                          u16* __restrict__ frag) {
    const int blk = blockIdx.x;
    const int mat = blk >> 5;
    const int nt  = (blk >> 2) & 7;
    const int kc  = blk & 3;
    const float* W = mat ? Wk : Wq;
    u16* dst = frag + mat * 16384 + (nt * 4 + kc) * 512;
    for (int i = threadIdx.x; i < 512; i += 256) {
        const int lane = i >> 3, j = i & 7;
        const int k = kc * 32 + ((lane >> 4) << 3) + j;
        const int n = nt * 16 + (lane & 15);
        dst[i] = f2u(W[k * 128 + n]);
    }
}

// ============ prep_wvl: Wvl = Wv@Wl (bf16), bvl = 32*bv@Wl + bl (f32) ============
// grid 129, 128 thr
__global__ void prep_wvl(const float* __restrict__ Wv, const float* __restrict__ bv,
                         const float* __restrict__ Wl, const float* __restrict__ bl,
                         u16* __restrict__ wvl, float* __restrict__ bvl) {
    const int d = threadIdx.x;
    const int e = blockIdx.x;
    if (e < 128) {
        float a = 0.f;
        for (int c = 0; c < 128; c++) a += Wv[e * 128 + c] * Wl[c * 128 + d];
        wvl[e * 128 + d] = f2u(a);
    } else {
        float a = bl[d];
        for (int c = 0; c < 128; c++) a += 32.f * bv[c] * Wl[c * 128 + d];
        bvl[d] = a;
    }
}

// ============ Kernel A: level-1 attention, MFMA proj+scores ============
// grid = 16384 (side = blk&1, walk = blk>>1), 256 thr
__global__ __launch_bounds__(256) void rwa_walk_mfma(
    const float* __restrict__ timef, const float* __restrict__ ppf,
    const float* __restrict__ pnf,  const float* __restrict__ wgt,
    const int*  __restrict__ sgn,
    const float* __restrict__ bq, const float* __restrict__ bk,
    const u16* __restrict__ frag,   // [2][8][4][64][8] bf16
    const u16* __restrict__ wvl, const float* __restrict__ bvl,
    u16* __restrict__ emb)          // bf16 [2*8192][128]
{
    // pad 136: row stride 272 B -> 16B-aligned rows, 4-bank rotation per row
    __shared__ __align__(16) u16 xs[32][136];
    __shared__ __align__(16) u16 qs[32][136];
    __shared__ __align__(16) u16 ks[32][136];
    __shared__ float sc[32][33];
    __shared__ float csumA[32];
    __shared__ float y1[128];
    __shared__ float part[2][128];

    const int t    = threadIdx.x;
    const int side = blockIdx.x & 1;
    const int bw   = blockIdx.x >> 1;
    const int tokb = bw * 32;
    const int wv   = t >> 6, lane = t & 63;

    // gather [pos/neg 19 | time 108 | weight 1], sign-selected, quantize bf16
    for (int o = t; o < 4096; o += 256) {
        const int l = o >> 7, f = o & 127;
        const int tok = tokb + l;
        float v;
        if (f < 19) {
            const bool takeP = (sgn[tok] > 0) == (side == 0);
            v = takeP ? ppf[tok * 19 + f] : pnf[tok * 19 + f];
        } else if (f < 127) {
            v = timef[tok * 108 + (f - 19)];
        } else {
            v = wgt[tok];
        }
        xs[l][f] = f2u(v);
    }
    __syncthreads();

    // Q/K projection: wave -> (mat = wv>>1: 0=Q 1=K, m-half = wv&1)
    {
        const int mat = wv >> 1, m0 = (wv & 1) << 4;
        const int row = m0 + (lane & 15);
        const int kq  = (lane >> 4) << 3;        // quad*8
        short8 afrag[4];
        #pragma unroll
        for (int kc = 0; kc < 4; kc++)
            afrag[kc] = *(const short8*)&xs[row][kc * 32 + kq];
        const float* bias = mat ? bk : bq;
        const u16* fb = frag + mat * 16384;
        u16 (* const outp)[136] = mat ? ks : qs;
        #pragma unroll
        for (int nt = 0; nt < 8; nt++) {
            const float bz = bias[nt * 16 + (lane & 15)];
            f32x4 acc = { bz, bz, bz, bz };
            #pragma unroll
            for (int kc = 0; kc < 4; kc++) {
                const short8 bfrag = *(const short8*)(fb + (((nt << 2) + kc) * 64 + lane) * 8);
                acc = __builtin_amdgcn_mfma_f32_16x16x32_bf16(afrag[kc], bfrag, acc, 0, 0, 0);
            }
            const int col = nt * 16 + (lane & 15);
            #pragma unroll
            for (int r = 0; r < 4; r++) {
                const int orow = m0 + ((lane >> 4) << 2) + r;   // C: row=(lane>>4)*4+reg
                outp[orow][col] = f2u(acc[r]);
            }
        }
    }
    __syncthreads();

    // scores = q k^T * SCALE : wave tile i0=(wv>>1)*16, j0=(wv&1)*16
    {
        const int i0 = (wv >> 1) << 4, j0 = (wv & 1) << 4;
        const int ra = i0 + (lane & 15);
        const int rb = j0 + (lane & 15);
        const int kq = (lane >> 4) << 3;
        f32x4 acc = { 0.f, 0.f, 0.f, 0.f };
        #pragma unroll
        for (int kc = 0; kc < 4; kc++) {
            const short8 a = *(const short8*)&qs[ra][kc * 32 + kq];
            const short8 b = *(const short8*)&ks[rb][kc * 32 + kq];
            acc = __builtin_amdgcn_mfma_f32_16x16x32_bf16(a, b, acc, 0, 0, 0);
        }
        #pragma unroll
        for (int r = 0; r < 4; r++)
            sc[i0 + ((lane >> 4) << 2) + r][j0 + (lane & 15)] = acc[r] * SCALE;
    }
    __syncthreads();

    if (t < 32) {   // softmax rows
        float m = -1e30f;
        for (int j = 0; j < 32; j++) m = fmaxf(m, sc[t][j]);
        float s = 0.f;
        for (int j = 0; j < 32; j++) { const float e0 = __expf(sc[t][j] - m); sc[t][j] = e0; s += e0; }
        const float inv = 1.f / s;
        for (int j = 0; j < 32; j++) sc[t][j] *= inv;
    }
    __syncthreads();
    if (t < 32) {   // column sums (query-sum folded onto keys)
        float s = 0.f;
        for (int i = 0; i < 32; i++) s += sc[i][t];
        csumA[t] = s;
    }
    __syncthreads();
    if (t < 128) {  // y1 = csumA^T @ x  (V-projection commuted out)
        float a = 0.f;
        for (int j = 0; j < 32; j++) a += csumA[j] * u2f(xs[j][t]);
        y1[t] = a;
    }
    __syncthreads();
    {   // part[h][d] = sum_{e in half h} y1[e] * Wvl[e][d]
        const int h = t >> 7, d = t & 127;
        float a = 0.f;
        for (int e = h * 64; e < h * 64 + 64; e++) a += y1[e] * u2f(wvl[e * 128 + d]);
        part[h][d] = a;
    }
    __syncthreads();
    if (t < 128) {  // emb row = y1@Wvl + bvl  (== (attnV)@Wl + bl)
        emb[(side * 8192 + bw) * 128 + t] = f2u(part[0][t] + part[1][t] + bvl[t]);
    }
}

// ============ Kernel B: level-2 attention, one block per (side, b) ============
__global__ __launch_bounds__(256) void rwa_path(
    const u16* __restrict__ embg,
    const float* __restrict__ Wqp, const float* __restrict__ bqp,
    const float* __restrict__ Wkp, const float* __restrict__ bkp,
    const float* __restrict__ Wvp, const float* __restrict__ bvp,
    float* __restrict__ out)
{
    __shared__ u16   embs[64][128];
    __shared__ float k2s[64][129];
    __shared__ float qrow[4][128];
    __shared__ float csum2[4][64];
    __shared__ float y2[128];

    const int t    = threadIdx.x;
    const int sb   = blockIdx.x;
    const int side = sb >> 7, b = sb & 127;
    const long gbase = (long)(side * 8192 + b * 64) * 128;
    const int wv_ = t >> 6, lane = t & 63;

    for (int o = t; o < 64 * 128; o += 256) embs[o >> 7][o & 127] = embg[gbase + o];
    __syncthreads();

    {   // k2 = emb @ Wkp + bkp
        const int d = t & 127, j0 = t >> 7;
        float ak2[32];
        const float bkv = bkp[d];
        #pragma unroll
        for (int i = 0; i < 32; i++) ak2[i] = bkv;
        for (int e = 0; e < 128; e++) {
            const float wk = Wkp[e * 128 + d];
            #pragma unroll
            for (int i = 0; i < 32; i++)
                ak2[i] += u2f(embs[j0 + 2 * i][e]) * wk;
        }
        #pragma unroll
        for (int i = 0; i < 32; i++) k2s[j0 + 2 * i][d] = ak2[i];
    }
    csum2[wv_][lane] = 0.f;
    __syncthreads();

    for (int i0 = 0; i0 < 64; i0 += 4) {
        const int r = i0 + wv_;
        {   // q2 row r on the fly (wave-private)
            float a0 = bqp[lane], a1 = bqp[lane + 64];
            for (int e = 0; e < 128; e++) {
                const float xv = u2f(embs[r][e]);
                a0 += xv * Wqp[e * 128 + lane];
                a1 += xv * Wqp[e * 128 + lane + 64];
            }
            qrow[wv_][lane] = a0; qrow[wv_][lane + 64] = a1;
        }
        {   // 64-key scores + in-wave softmax, accumulate column sums
            const int j = lane;
            float s = 0.f;
            for (int e = 0; e < 128; e += 4) {
                const float4 q4 = *(const float4*)&qrow[wv_][e];
                s += q4.x * k2s[j][e]     + q4.y * k2s[j][e + 1]
                   + q4.z * k2s[j][e + 2] + q4.w * k2s[j][e + 3];
            }
            s *= SCALE;
            float m = s;
            #pragma unroll
            for (int off = 32; off; off >>= 1) m = fmaxf(m, __shfl_xor(m, off));
            const float e0 = __expf(s - m);
            float sum = e0;
            #pragma unroll
            for (int off = 32; off; off >>= 1) sum += __shfl_xor(sum, off);
            csum2[wv_][j] += e0 / sum;
        }
        __syncthreads();
    }

    if (t < 64)
        csum2[0][t] = csum2[0][t] + csum2[1][t] + csum2[2][t] + csum2[3][t];
    __syncthreads();
    if (t < 128) {
        float a = 0.f;
        for (int j = 0; j < 64; j++) a += csum2[0][j] * u2f(embs[j][t]);
        y2[t] = a;
    }
    __syncthreads();
    if (t < 128) {
        float a = 64.f * bvp[t];
        for (int e = 0; e < 128; e++) a += y2[e] * Wvp[e * 128 + t];
        out[sb * 128 + t] = a;
    }
}

// ============ Fallback: R3's proven fused kernel (used only if ws too small) ============
__global__ __launch_bounds__(256) void rwa_fused_fb(
    const float* timef, const float* ppf, const float* pnf, const float* wgt,
    const int* __restrict__ sgn,
    const float* Wq, const float* bq, const float* Wk, const float* bk,
    const float* Wv, const float* bv, const float* Wl, const float* bl,
    const float* Wqp, const float* bqp, const float* Wkp, const float* bkp,
    const float* Wvp, const float* bvp, float* out)
{
    extern __shared__ __align__(16) char S[];
    char* const U = S;
    float (* const sc)[33]     = (float(*)[33])(S + 41088);
    u16   (* const embs)[128]  = (u16  (*)[128])(S + 45312);
    float* const csumA         = (float*)(S + 61696);
    float* const y1            = (float*)(S + 61824);
    float* const e1            = (float*)(S + 62336);
    u16   (* const xs)[128]   = (u16  (*)[128])U;
    float (* const qs)[128]   = (float(*)[128])(U + 8192);
    float (* const ks)[129]   = (float(*)[129])(U + 8192 + 16384);
    float (* const k2s)[129]  = (float(*)[129])U;
    float (* const qrow)[128] = (float(*)[128])(U + 33024);
    float (* const csum2)[64] = (float(*)[64])(U + 35072);

    const int t    = threadIdx.x;
    const int side = blockIdx.x >> 7;
    const int b    = blockIdx.x & 127;
    const int wv_  = t >> 6;
    const int lane = t & 63;

    for (int w = 0; w < 64; ++w) {
        const int tokb = (b * 64 + w) * 32;
        for (int o = t; o < 32 * 128; o += 256) {
            const int l = o >> 7, f = o & 127;
            const int tok = tokb + l;
            float v;
            if (f < 19) {
                const bool takeP = (sgn[tok] > 0) == (side == 0);
                v = takeP ? ppf[tok * 19 + f] : pnf[tok * 19 + f];
            } else if (f < 127) v = timef[tok * 108 + (f - 19)];
            else v = wgt[tok];
            xs[l][f] = f2u(v);
        }
        __syncthreads();
        {
            const int d = t & 127, l0 = t >> 7;
            float aq[16], ak[16];
            const float bqv = bq[d], bkv = bk[d];
            #pragma unroll
            for (int i = 0; i < 16; i++) { aq[i] = bqv; ak[i] = bkv; }
            for (int e = 0; e < 128; e += 4) {
                float xv[16][4];
                #pragma unroll
                for (int i = 0; i < 16; i++) {
                    const ushort4 u = *(const ushort4*)&xs[l0 + 2 * i][e];
                    xv[i][0] = u2f(u.x); xv[i][1] = u2f(u.y);
                    xv[i][2] = u2f(u.z); xv[i][3] = u2f(u.w);
                }
                #pragma unroll
                for (int r = 0; r < 4; r++) {
                    const float wq = Wq[(e + r) * 128 + d];
                    const float wk = Wk[(e + r) * 128 + d];
                    #pragma unroll
                    for (int i = 0; i < 16; i++) {
                        aq[i] += xv[i][r] * wq; ak[i] += xv[i][r] * wk;
                    }
                }
            }
            #pragma unroll
            for (int i = 0; i < 16; i++) { const int l = l0 + 2 * i; qs[l][d] = aq[i]; ks[l][d] = ak[i]; }
        }
        __syncthreads();
        for (int o = t; o < 1024; o += 256) {
            const int i = o >> 5, j = o & 31;
            float a0 = 0, a1 = 0, a2 = 0, a3 = 0;
            for (int e = 0; e < 128; e += 4) {
                const float4 q4 = *(const float4*)&qs[i][e];
                a0 += q4.x * ks[j][e];     a1 += q4.y * ks[j][e + 1];
                a2 += q4.z * ks[j][e + 2]; a3 += q4.w * ks[j][e + 3];
            }
            sc[i][j] = (a0 + a1 + a2 + a3) * SCALE;
        }
        __syncthreads();
        if (t < 32) {
            float m = -1e30f;
            for (int j = 0; j < 32; j++) m = fmaxf(m, sc[t][j]);
            float s = 0.f;
            for (int j = 0; j < 32; j++) { const float e0 = __expf(sc[t][j] - m); sc[t][j] = e0; s += e0; }
            const float inv = 1.f / s;
            for (int j = 0; j < 32; j++) sc[t][j] *= inv;
        }
        __syncthreads();
        if (t < 32) { float s = 0.f; for (int i = 0; i < 32; i++) s += sc[i][t]; csumA[t] = s; }
        __syncthreads();
        if (t < 128) { float a = 0.f; for (int j = 0; j < 32; j++) a += csumA[j] * u2f(xs[j][t]); y1[t] = a; }
        __syncthreads();
        if (t < 128) {
            float a = 32.f * bv[t];
            for (int e = 0; e < 128; e++) a += y1[e] * Wv[e * 128 + t];
            e1[t] = a;
        }
        __syncthreads();
        if (t < 128) {
            float a = bl[t];
            for (int f = 0; f < 128; f++) a += e1[f] * Wl[f * 128 + t];
            embs[w][t] = f2u(a);
        }
        __syncthreads();
    }
    {
        const int d = t & 127, j0 = t >> 7;
        float ak2[32];
        const float bkv = bkp[d];
        #pragma unroll
        for (int i = 0; i < 32; i++) ak2[i] = bkv;
        for (int e = 0; e < 128; e++) {
            const float wk = Wkp[e * 128 + d];
            #pragma unroll
            for (int i = 0; i < 32; i++) ak2[i] += u2f(embs[j0 + 2 * i][e]) * wk;
        }
        #pragma unroll
        for (int i = 0; i < 32; i++) k2s[j0 + 2 * i][d] = ak2[i];
    }
    csum2[wv_][lane] = 0.f;
    __syncthreads();
    for (int i0 = 0; i0 < 64; i0 += 4) {
        const int r = i0 + wv_;
        {
            float a0 = bqp[lane], a1 = bqp[lane + 64];
            for (int e = 0; e < 128; e++) {
                const float xv = u2f(embs[r][e]);
                a0 += xv * Wqp[e * 128 + lane];
                a1 += xv * Wqp[e * 128 + lane + 64];
            }
            qrow[wv_][lane] = a0; qrow[wv_][lane + 64] = a1;
        }
        {
            const int j = lane;
            float s = 0.f;
            for (int e = 0; e < 128; e += 4) {
                const float4 q4 = *(const float4*)&qrow[wv_][e];
                s += q4.x * k2s[j][e] + q4.y * k2s[j][e + 1] + q4.z * k2s[j][e + 2] + q4.w * k2s[j][e + 3];
            }
            s *= SCALE;
            float m = s;
            #pragma unroll
            for (int off = 32; off; off >>= 1) m = fmaxf(m, __shfl_xor(m, off));
            const float e0 = __expf(s - m);
            float sum = e0;
            #pragma unroll
            for (int off = 32; off; off >>= 1) sum += __shfl_xor(sum, off);
            csum2[wv_][j] += e0 / sum;
        }
        __syncthreads();
    }
    if (t < 64) csum2[0][t] = csum2[0][t] + csum2[1][t] + csum2[2][t] + csum2[3][t];
    __syncthreads();
    if (t < 128) { float a = 0.f; for (int j = 0; j < 64; j++) a += csum2[0][j] * u2f(embs[j][t]); y1[t] = a; }
    __syncthreads();
    if (t < 128) {
        float a = 64.f * bvp[t];
        for (int e = 0; e < 128; e++) a += y1[e] * Wvp[e * 128 + t];
        out[blockIdx.x * 128 + t] = a;
    }
}

extern "C" void kernel_launch(void* const* d_in, const int* in_sizes, int n_in,
                              void* d_out, int out_size, void* d_ws, size_t ws_size,
                              hipStream_t stream) {
    const float* timef = (const float*)d_in[0];
    const float* ppf   = (const float*)d_in[1];
    const float* pnf   = (const float*)d_in[2];
    const float* wgt   = (const float*)d_in[3];
    const int*   sgn   = (const int*)  d_in[4];
    const float* Wq  = (const float*)d_in[5];  const float* bq  = (const float*)d_in[6];
    const float* Wk  = (const float*)d_in[7];  const float* bk  = (const float*)d_in[8];
    const float* Wv  = (const float*)d_in[9];  const float* bv  = (const float*)d_in[10];
    const float* Wl  = (const float*)d_in[11]; const float* bl  = (const float*)d_in[12];
    const float* Wqp = (const float*)d_in[13]; const float* bqp = (const float*)d_in[14];
    const float* Wkp = (const float*)d_in[15]; const float* bkp = (const float*)d_in[16];
    const float* Wvp = (const float*)d_in[17]; const float* bvp = (const float*)d_in[18];
    float* out = (float*)d_out;
    (void)in_sizes; (void)n_in; (void)out_size;

    // ws layout: frag u16[32768] (64KB) | wvl u16[16384] (32KB) | bvl f32[128] (512B)
    //            | emb bf16 [2*8192*128] (4MB) at offset 128KB
    const size_t need = (size_t)(128 * 1024) + (size_t)2 * 8192 * 128 * sizeof(u16);
    if (ws_size >= need) {
        u16*   frag = (u16*)d_ws;
        u16*   wvl  = (u16*)((char*)d_ws + 64 * 1024);
        float* bvl  = (float*)((char*)d_ws + 96 * 1024);
        u16*   emb  = (u16*)((char*)d_ws + 128 * 1024);
        hipLaunchKernelGGL(prep_frag, dim3(64), dim3(256), 0, stream, Wq, Wk, frag);
        hipLaunchKernelGGL(prep_wvl, dim3(129), dim3(128), 0, stream, Wv, bv, Wl, bl, wvl, bvl);
        hipLaunchKernelGGL(rwa_walk_mfma, dim3(16384), dim3(256), 0, stream,
                           timef, ppf, pnf, wgt, sgn, bq, bk, frag, wvl, bvl, emb);
        hipLaunchKernelGGL(rwa_path, dim3(256), dim3(256), 0, stream,
                           emb, Wqp, bqp, Wkp, bkp, Wvp, bvp, out);
    } else {
        hipLaunchKernelGGL(rwa_fused_fb, dim3(256), dim3(256), 62848, stream,
                           timef, ppf, pnf, wgt, sgn, Wq, bq, Wk, bk, Wv, bv, Wl, bl,
                           Wqp, bqp, Wkp, bkp, Wvp, bvp, out);
    }
}

// Round 6
// 514.908 us; speedup vs baseline: 4.5167x; 1.2383x over previous
//
#include <hip/hip_runtime.h>
#include <hip/hip_bf16.h>

typedef __hip_bfloat16 bf16;
typedef unsigned short u16;
typedef unsigned int   u32;
typedef __attribute__((ext_vector_type(8))) short short8;   // 8 bf16 = 4 VGPRs
typedef __attribute__((ext_vector_type(4))) float f32x4;

#define SCALE 0.08838834764831845f  // 1/sqrt(128)

__device__ __forceinline__ float u2f(u16 x) { return __uint_as_float(((u32)x) << 16); }
__device__ __forceinline__ u16   f2u(float f) {
    __hip_bfloat16 h = __float2bfloat16(f);
    return *reinterpret_cast<u16*>(&h);
}

// ============ prep_frag: fragment-major bf16 repack of Wq,Wk,Wqp,Wkp ============
// frag[mat][nt][kc][lane][j] = W[kc*32 + (lane>>4)*8 + j][nt*16 + (lane&15)]
// grid 128 = 4 mats x 8 nt x 4 kc, 256 thr
__global__ void prep_frag(const float* __restrict__ Wq, const float* __restrict__ Wk,
                          const float* __restrict__ Wqp, const float* __restrict__ Wkp,
                          u16* __restrict__ frag) {
    const int blk = blockIdx.x;
    const int mat = blk >> 5;
    const int nt  = (blk >> 2) & 7;
    const int kc  = blk & 3;
    const float* W = (mat == 0) ? Wq : (mat == 1) ? Wk : (mat == 2) ? Wqp : Wkp;
    u16* dst = frag + mat * 16384 + (nt * 4 + kc) * 512;
    for (int i = threadIdx.x; i < 512; i += 256) {
        const int lane = i >> 3, j = i & 7;
        const int k = kc * 32 + ((lane >> 4) << 3) + j;
        const int n = nt * 16 + (lane & 15);
        dst[i] = f2u(W[k * 128 + n]);
    }
}

// ============ prep_wvl: Wvl = Wv@Wl (bf16), bvl = 32*bv@Wl + bl (f32) ============
__global__ void prep_wvl(const float* __restrict__ Wv, const float* __restrict__ bv,
                         const float* __restrict__ Wl, const float* __restrict__ bl,
                         u16* __restrict__ wvl, float* __restrict__ bvl) {
    const int d = threadIdx.x;
    const int e = blockIdx.x;
    if (e < 128) {
        float a = 0.f;
        for (int c = 0; c < 128; c++) a += Wv[e * 128 + c] * Wl[c * 128 + d];
        wvl[e * 128 + d] = f2u(a);
    } else {
        float a = bl[d];
        for (int c = 0; c < 128; c++) a += 32.f * bv[c] * Wl[c * 128 + d];
        bvl[d] = a;
    }
}

// ============ Kernel A: level-1, BOTH sides per walk-block ============
// grid = 8192 (walk), 512 thr: waves 0-3 side0, waves 4-7 side1
__global__ __launch_bounds__(512) void rwa_walk2(
    const float* __restrict__ timef, const float* __restrict__ ppf,
    const float* __restrict__ pnf,  const float* __restrict__ wgt,
    const int*  __restrict__ sgn,
    const float* __restrict__ bq, const float* __restrict__ bk,
    const u16* __restrict__ frag,   // [4][8][4][64][8] bf16 (mats 0,1 used here)
    const u16* __restrict__ wvl, const float* __restrict__ bvl,
    u16* __restrict__ emb)          // bf16 [2*8192][128]
{
    __shared__ __align__(16) u16 xs[2][32][136];   // 17408 B
    __shared__ __align__(16) u16 qs[2][32][136];   // 17408
    __shared__ __align__(16) u16 ks[2][32][136];   // 17408
    __shared__ float sc[2][32][33];                // 8448
    __shared__ float csum[2][32];                  // 256
    __shared__ float y1[2][128];                   // 1024
    __shared__ float part[2][2][128];              // 2048   => 64000 B total
    const int t    = threadIdx.x;
    const int bw   = blockIdx.x;
    const int tokb = bw * 32;
    const int wv   = t >> 6, lane = t & 63;
    const int side = wv >> 2, w2 = wv & 3;

    // ---- shared gather: time/weight once, pos/neg sign-routed to both sides ----
    for (int o = t; o < 4096; o += 512) {
        const int l = o >> 7, f = o & 127;
        const int tok = tokb + l;
        if (f < 19) {
            const u16 up = f2u(ppf[tok * 19 + f]);
            const u16 un = f2u(pnf[tok * 19 + f]);
            const bool sp = sgn[tok] > 0;
            xs[0][l][f] = sp ? up : un;
            xs[1][l][f] = sp ? un : up;
        } else {
            const float v = (f < 127) ? timef[tok * 108 + (f - 19)] : wgt[tok];
            const u16 uv = f2u(v);
            xs[0][l][f] = uv;
            xs[1][l][f] = uv;
        }
    }
    __syncthreads();

    // ---- Q/K projection (MFMA): per side, wave -> (mat = w2>>1, m-half = w2&1) ----
    {
        const int mat = w2 >> 1, m0 = (w2 & 1) << 4;
        const int row = m0 + (lane & 15);
        const int kq  = (lane >> 4) << 3;
        short8 afrag[4];
        #pragma unroll
        for (int kc = 0; kc < 4; kc++)
            afrag[kc] = *(const short8*)&xs[side][row][kc * 32 + kq];
        const float* bias = mat ? bk : bq;
        const u16* fb = frag + mat * 16384;
        u16 (* const outp)[136] = mat ? ks[side] : qs[side];
        #pragma unroll
        for (int nt = 0; nt < 8; nt++) {
            const float bz = bias[nt * 16 + (lane & 15)];
            f32x4 acc = { bz, bz, bz, bz };
            #pragma unroll
            for (int kc = 0; kc < 4; kc++) {
                const short8 bfrag = *(const short8*)(fb + (((nt << 2) + kc) * 64 + lane) * 8);
                acc = __builtin_amdgcn_mfma_f32_16x16x32_bf16(afrag[kc], bfrag, acc, 0, 0, 0);
            }
            const int col = nt * 16 + (lane & 15);
            #pragma unroll
            for (int r = 0; r < 4; r++)
                outp[m0 + ((lane >> 4) << 2) + r][col] = f2u(acc[r]);
        }
    }
    __syncthreads();

    // ---- scores = q k^T * SCALE (MFMA), tile (i0,j0) per wave ----
    {
        const int i0 = (w2 >> 1) << 4, j0 = (w2 & 1) << 4;
        const int ra = i0 + (lane & 15), rb = j0 + (lane & 15);
        const int kq = (lane >> 4) << 3;
        f32x4 acc = { 0.f, 0.f, 0.f, 0.f };
        #pragma unroll
        for (int kc = 0; kc < 4; kc++) {
            const short8 a = *(const short8*)&qs[side][ra][kc * 32 + kq];
            const short8 b = *(const short8*)&ks[side][rb][kc * 32 + kq];
            acc = __builtin_amdgcn_mfma_f32_16x16x32_bf16(a, b, acc, 0, 0, 0);
        }
        #pragma unroll
        for (int r = 0; r < 4; r++)
            sc[side][i0 + ((lane >> 4) << 2) + r][j0 + (lane & 15)] = acc[r] * SCALE;
    }
    __syncthreads();

    if ((t & 255) < 32) {   // softmax rows: side0 on wave0, side1 on wave4
        const int s = t >> 8, row = t & 31;
        float m = -1e30f;
        for (int j = 0; j < 32; j++) m = fmaxf(m, sc[s][row][j]);
        float sum = 0.f;
        for (int j = 0; j < 32; j++) { const float e0 = __expf(sc[s][row][j] - m); sc[s][row][j] = e0; sum += e0; }
        const float inv = 1.f / sum;
        for (int j = 0; j < 32; j++) sc[s][row][j] *= inv;
    }
    __syncthreads();
    if ((t & 255) < 32) {   // column sums
        const int s = t >> 8, col = t & 31;
        float sum = 0.f;
        for (int i = 0; i < 32; i++) sum += sc[s][i][col];
        csum[s][col] = sum;
    }
    __syncthreads();
    if ((t & 255) < 128) {  // y1 = csum^T @ x
        const int s = t >> 8, d = t & 127;
        float a = 0.f;
        for (int j = 0; j < 32; j++) a += csum[s][j] * u2f(xs[s][j][d]);
        y1[s][d] = a;
    }
    __syncthreads();
    {   // part[s][h][d] over half of e; all 8 waves busy
        const int s = t >> 8, h = (t >> 7) & 1, d = t & 127;
        float a = 0.f;
        for (int e = h * 64; e < h * 64 + 64; e++) a += y1[s][e] * u2f(wvl[e * 128 + d]);
        part[s][h][d] = a;
    }
    __syncthreads();
    if ((t & 255) < 128) {  // emb = y1@Wvl + bvl
        const int s = t >> 8, d = t & 127;
        emb[(s * 8192 + bw) * 128 + d] = f2u(part[s][0][d] + part[s][1][d] + bvl[d]);
    }
}

// ============ Kernel B: level-2 attention, MFMA, one block per (side,b) ============
__global__ __launch_bounds__(256) void rwa_path2(
    const u16* __restrict__ embg,
    const u16* __restrict__ frag,    // mats 2 (Wqp), 3 (Wkp)
    const float* __restrict__ bqp, const float* __restrict__ bkp,
    const float* __restrict__ Wvp, const float* __restrict__ bvp,
    float* __restrict__ out)
{
    // U: embs u16[64][136] (17408) union sc2 f32[64][65] (16640)
    __shared__ __align__(16) char Ubuf[17408];
    __shared__ __align__(16) u16 q2s[64][136];
    __shared__ __align__(16) u16 k2s[64][136];
    __shared__ float csum[64];
    __shared__ float y2[128];
    u16   (* const embs)[136] = (u16  (*)[136])Ubuf;
    float (* const sc2)[65]   = (float(*)[65])Ubuf;

    const int t  = threadIdx.x;
    const int sb = blockIdx.x;               // side*128 + b
    const long gbase = (long)sb * 64 * 128;
    const int wv = t >> 6, lane = t & 63;

    // ---- load emb (bf16) ----
    for (int o = t * 4; o < 8192; o += 1024)
        *(ushort4*)&embs[o >> 7][o & 127] = *(const ushort4*)(embg + gbase + o);
    __syncthreads();

    // ---- q2/k2 = emb @ W + b (MFMA): wave -> mat = wv>>1, row-tiles {wv&1, wv&1+2} ----
    {
        const int mat = wv >> 1;
        const float* bias = mat ? bkp : bqp;
        const u16* fb = frag + (2 + mat) * 16384;
        u16 (* const outp)[136] = mat ? k2s : q2s;
        const int kq = (lane >> 4) << 3;
        #pragma unroll
        for (int rr = 0; rr < 2; rr++) {
            const int m0 = ((wv & 1) + 2 * rr) << 4;
            const int row = m0 + (lane & 15);
            short8 afrag[4];
            #pragma unroll
            for (int kc = 0; kc < 4; kc++)
                afrag[kc] = *(const short8*)&embs[row][kc * 32 + kq];
            #pragma unroll
            for (int nt = 0; nt < 8; nt++) {
                const float bz = bias[nt * 16 + (lane & 15)];
                f32x4 acc = { bz, bz, bz, bz };
                #pragma unroll
                for (int kc = 0; kc < 4; kc++) {
                    const short8 bfrag = *(const short8*)(fb + (((nt << 2) + kc) * 64 + lane) * 8);
                    acc = __builtin_amdgcn_mfma_f32_16x16x32_bf16(afrag[kc], bfrag, acc, 0, 0, 0);
                }
                const int col = nt * 16 + (lane & 15);
                #pragma unroll
                for (int r = 0; r < 4; r++)
                    outp[m0 + ((lane >> 4) << 2) + r][col] = f2u(acc[r]);
            }
        }
    }
    __syncthreads();

    // ---- scores 64x64 (MFMA): wave w -> row-tile w, all 4 col-tiles; embs now dead -> sc2 ----
    {
        const int i0 = wv << 4;
        const int ra = i0 + (lane & 15);
        const int kq = (lane >> 4) << 3;
        short8 a[4];
        #pragma unroll
        for (int kc = 0; kc < 4; kc++)
            a[kc] = *(const short8*)&q2s[ra][kc * 32 + kq];
        #pragma unroll
        for (int jt = 0; jt < 4; jt++) {
            const int rb = (jt << 4) + (lane & 15);
            f32x4 acc = { 0.f, 0.f, 0.f, 0.f };
            #pragma unroll
            for (int kc = 0; kc < 4; kc++) {
                const short8 b = *(const short8*)&k2s[rb][kc * 32 + kq];
                acc = __builtin_amdgcn_mfma_f32_16x16x32_bf16(a[kc], b, acc, 0, 0, 0);
            }
            #pragma unroll
            for (int r = 0; r < 4; r++)
                sc2[i0 + ((lane >> 4) << 2) + r][(jt << 4) + (lane & 15)] = acc[r] * SCALE;
        }
    }
    __syncthreads();

    // ---- softmax: wave handles 16 rows, 4 lanes per row ----
    {
        const int row = (wv << 4) + (lane >> 2), sub = lane & 3;
        float m = -1e30f;
        #pragma unroll 4
        for (int i = 0; i < 16; i++) m = fmaxf(m, sc2[row][sub + 4 * i]);
        m = fmaxf(m, __shfl_xor(m, 1)); m = fmaxf(m, __shfl_xor(m, 2));
        float sum = 0.f;
        float ex[16];
        #pragma unroll 4
        for (int i = 0; i < 16; i++) { ex[i] = __expf(sc2[row][sub + 4 * i] - m); sum += ex[i]; }
        sum += __shfl_xor(sum, 1); sum += __shfl_xor(sum, 2);
        const float inv = 1.f / sum;
        #pragma unroll 4
        for (int i = 0; i < 16; i++) sc2[row][sub + 4 * i] = ex[i] * inv;
    }
    __syncthreads();
    if (t < 64) {   // column sums
        float s = 0.f;
        for (int i = 0; i < 64; i++) s += sc2[i][t];
        csum[t] = s;
    }
    __syncthreads();
    // ---- reload embs (sc2 dead again) ----
    for (int o = t * 4; o < 8192; o += 1024)
        *(ushort4*)&embs[o >> 7][o & 127] = *(const ushort4*)(embg + gbase + o);
    __syncthreads();
    if (t < 128) {  // y2 = csum^T @ emb
        float a = 0.f;
        for (int j = 0; j < 64; j++) a += csum[j] * u2f(embs[j][t]);
        y2[t] = a;
    }
    __syncthreads();
    if (t < 128) {  // out = y2 @ Wvp + 64*bvp
        float a = 64.f * bvp[t];
        for (int e = 0; e < 128; e++) a += y2[e] * Wvp[e * 128 + t];
        out[sb * 128 + t] = a;
    }
}

// ============ Fallback: R3's proven fused kernel (used only if ws too small) ============
__global__ __launch_bounds__(256) void rwa_fused_fb(
    const float* timef, const float* ppf, const float* pnf, const float* wgt,
    const int* __restrict__ sgn,
    const float* Wq, const float* bq, const float* Wk, const float* bk,
    const float* Wv, const float* bv, const float* Wl, const float* bl,
    const float* Wqp, const float* bqp, const float* Wkp, const float* bkp,
    const float* Wvp, const float* bvp, float* out)
{
    extern __shared__ __align__(16) char S[];
    char* const U = S;
    float (* const sc)[33]     = (float(*)[33])(S + 41088);
    u16   (* const embs)[128]  = (u16  (*)[128])(S + 45312);
    float* const csumA         = (float*)(S + 61696);
    float* const y1            = (float*)(S + 61824);
    float* const e1            = (float*)(S + 62336);
    u16   (* const xs)[128]   = (u16  (*)[128])U;
    float (* const qs)[128]   = (float(*)[128])(U + 8192);
    float (* const ks)[129]   = (float(*)[129])(U + 8192 + 16384);
    float (* const k2s)[129]  = (float(*)[129])U;
    float (* const qrow)[128] = (float(*)[128])(U + 33024);
    float (* const csum2)[64] = (float(*)[64])(U + 35072);

    const int t    = threadIdx.x;
    const int side = blockIdx.x >> 7;
    const int b    = blockIdx.x & 127;
    const int wv_  = t >> 6;
    const int lane = t & 63;

    for (int w = 0; w < 64; ++w) {
        const int tokb = (b * 64 + w) * 32;
        for (int o = t; o < 32 * 128; o += 256) {
            const int l = o >> 7, f = o & 127;
            const int tok = tokb + l;
            float v;
            if (f < 19) {
                const bool takeP = (sgn[tok] > 0) == (side == 0);
                v = takeP ? ppf[tok * 19 + f] : pnf[tok * 19 + f];
            } else if (f < 127) v = timef[tok * 108 + (f - 19)];
            else v = wgt[tok];
            xs[l][f] = f2u(v);
        }
        __syncthreads();
        {
            const int d = t & 127, l0 = t >> 7;
            float aq[16], ak[16];
            const float bqv = bq[d], bkv = bk[d];
            #pragma unroll
            for (int i = 0; i < 16; i++) { aq[i] = bqv; ak[i] = bkv; }
            for (int e = 0; e < 128; e += 4) {
                float xv[16][4];
                #pragma unroll
                for (int i = 0; i < 16; i++) {
                    const ushort4 u = *(const ushort4*)&xs[l0 + 2 * i][e];
                    xv[i][0] = u2f(u.x); xv[i][1] = u2f(u.y);
                    xv[i][2] = u2f(u.z); xv[i][3] = u2f(u.w);
                }
                #pragma unroll
                for (int r = 0; r < 4; r++) {
                    const float wq = Wq[(e + r) * 128 + d];
                    const float wk = Wk[(e + r) * 128 + d];
                    #pragma unroll
                    for (int i = 0; i < 16; i++) {
                        aq[i] += xv[i][r] * wq; ak[i] += xv[i][r] * wk;
                    }
                }
            }
            #pragma unroll
            for (int i = 0; i < 16; i++) { const int l = l0 + 2 * i; qs[l][d] = aq[i]; ks[l][d] = ak[i]; }
        }
        __syncthreads();
        for (int o = t; o < 1024; o += 256) {
            const int i = o >> 5, j = o & 31;
            float a0 = 0, a1 = 0, a2 = 0, a3 = 0;
            for (int e = 0; e < 128; e += 4) {
                const float4 q4 = *(const float4*)&qs[i][e];
                a0 += q4.x * ks[j][e];     a1 += q4.y * ks[j][e + 1];
                a2 += q4.z * ks[j][e + 2]; a3 += q4.w * ks[j][e + 3];
            }
            sc[i][j] = (a0 + a1 + a2 + a3) * SCALE;
        }
        __syncthreads();
        if (t < 32) {
            float m = -1e30f;
            for (int j = 0; j < 32; j++) m = fmaxf(m, sc[t][j]);
            float s = 0.f;
            for (int j = 0; j < 32; j++) { const float e0 = __expf(sc[t][j] - m); sc[t][j] = e0; s += e0; }
            const float inv = 1.f / s;
            for (int j = 0; j < 32; j++) sc[t][j] *= inv;
        }
        __syncthreads();
        if (t < 32) { float s = 0.f; for (int i = 0; i < 32; i++) s += sc[i][t]; csumA[t] = s; }
        __syncthreads();
        if (t < 128) { float a = 0.f; for (int j = 0; j < 32; j++) a += csumA[j] * u2f(xs[j][t]); y1[t] = a; }
        __syncthreads();
        if (t < 128) {
            float a = 32.f * bv[t];
            for (int e = 0; e < 128; e++) a += y1[e] * Wv[e * 128 + t];
            e1[t] = a;
        }
        __syncthreads();
        if (t < 128) {
            float a = bl[t];
            for (int f = 0; f < 128; f++) a += e1[f] * Wl[f * 128 + t];
            embs[w][t] = f2u(a);
        }
        __syncthreads();
    }
    {
        const int d = t & 127, j0 = t >> 7;
        float ak2[32];
        const float bkv = bkp[d];
        #pragma unroll
        for (int i = 0; i < 32; i++) ak2[i] = bkv;
        for (int e = 0; e < 128; e++) {
            const float wk = Wkp[e * 128 + d];
            #pragma unroll
            for (int i = 0; i < 32; i++) ak2[i] += u2f(embs[j0 + 2 * i][e]) * wk;
        }
        #pragma unroll
        for (int i = 0; i < 32; i++) k2s[j0 + 2 * i][d] = ak2[i];
    }
    csum2[wv_][lane] = 0.f;
    __syncthreads();
    for (int i0 = 0; i0 < 64; i0 += 4) {
        const int r = i0 + wv_;
        {
            float a0 = bqp[lane], a1 = bqp[lane + 64];
            for (int e = 0; e < 128; e++) {
                const float xv = u2f(embs[r][e]);
                a0 += xv * Wqp[e * 128 + lane];
                a1 += xv * Wqp[e * 128 + lane + 64];
            }
            qrow[wv_][lane] = a0; qrow[wv_][lane + 64] = a1;
        }
        {
            const int j = lane;
            float s = 0.f;
            for (int e = 0; e < 128; e += 4) {
                const float4 q4 = *(const float4*)&qrow[wv_][e];
                s += q4.x * k2s[j][e] + q4.y * k2s[j][e + 1] + q4.z * k2s[j][e + 2] + q4.w * k2s[j][e + 3];
            }
            s *= SCALE;
            float m = s;
            #pragma unroll
            for (int off = 32; off; off >>= 1) m = fmaxf(m, __shfl_xor(m, off));
            const float e0 = __expf(s - m);
            float sum = e0;
            #pragma unroll
            for (int off = 32; off; off >>= 1) sum += __shfl_xor(sum, off);
            csum2[wv_][j] += e0 / sum;
        }
        __syncthreads();
    }
    if (t < 64) csum2[0][t] = csum2[0][t] + csum2[1][t] + csum2[2][t] + csum2[3][t];
    __syncthreads();
    if (t < 128) { float a = 0.f; for (int j = 0; j < 64; j++) a += csum2[0][j] * u2f(embs[j][t]); y1[t] = a; }
    __syncthreads();
    if (t < 128) {
        float a = 64.f * bvp[t];
        for (int e = 0; e < 128; e++) a += y1[e] * Wvp[e * 128 + t];
        out[blockIdx.x * 128 + t] = a;
    }
}

extern "C" void kernel_launch(void* const* d_in, const int* in_sizes, int n_in,
                              void* d_out, int out_size, void* d_ws, size_t ws_size,
                              hipStream_t stream) {
    const float* timef = (const float*)d_in[0];
    const float* ppf   = (const float*)d_in[1];
    const float* pnf   = (const float*)d_in[2];
    const float* wgt   = (const float*)d_in[3];
    const int*   sgn   = (const int*)  d_in[4];
    const float* Wq  = (const float*)d_in[5];  const float* bq  = (const float*)d_in[6];
    const float* Wk  = (const float*)d_in[7];  const float* bk  = (const float*)d_in[8];
    const float* Wv  = (const float*)d_in[9];  const float* bv  = (const float*)d_in[10];
    const float* Wl  = (const float*)d_in[11]; const float* bl  = (const float*)d_in[12];
    const float* Wqp = (const float*)d_in[13]; const float* bqp = (const float*)d_in[14];
    const float* Wkp = (const float*)d_in[15]; const float* bkp = (const float*)d_in[16];
    const float* Wvp = (const float*)d_in[17]; const float* bvp = (const float*)d_in[18];
    float* out = (float*)d_out;
    (void)in_sizes; (void)n_in; (void)out_size;

    // ws: frag u16[4*16384] (128KB) | wvl u16[16384] (32KB) | bvl f32[128] (512B) | emb bf16 (4MB)
    const size_t need = (size_t)(192 * 1024) + (size_t)2 * 8192 * 128 * sizeof(u16);
    if (ws_size >= need) {
        u16*   frag = (u16*)d_ws;
        u16*   wvl  = (u16*)((char*)d_ws + 128 * 1024);
        float* bvl  = (float*)((char*)d_ws + 160 * 1024);
        u16*   emb  = (u16*)((char*)d_ws + 192 * 1024);
        hipLaunchKernelGGL(prep_frag, dim3(128), dim3(256), 0, stream, Wq, Wk, Wqp, Wkp, frag);
        hipLaunchKernelGGL(prep_wvl, dim3(129), dim3(128), 0, stream, Wv, bv, Wl, bl, wvl, bvl);
        hipLaunchKernelGGL(rwa_walk2, dim3(8192), dim3(512), 0, stream,
                           timef, ppf, pnf, wgt, sgn, bq, bk, frag, wvl, bvl, emb);
        hipLaunchKernelGGL(rwa_path2, dim3(256), dim3(256), 0, stream,
                           emb, frag, bqp, bkp, Wvp, bvp, out);
    } else {
        hipLaunchKernelGGL(rwa_fused_fb, dim3(256), dim3(256), 62848, stream,
                           timef, ppf, pnf, wgt, sgn, Wq, bq, Wk, bk, Wv, bv, Wl, bl,
                           Wqp, bqp, Wkp, bkp, Wvp, bvp, out);
    }
}